// Round 9
// baseline (431.216 us; speedup 1.0000x reference)
//
#include <hip/hip_runtime.h>

#define FEAT 128

typedef __attribute__((ext_vector_type(8))) short short8;   // 8 bf16 = 4 VGPRs
typedef __attribute__((ext_vector_type(4))) float f32x4;

__device__ __forceinline__ unsigned int bf16rtn(float f) {
    unsigned int u = __float_as_uint(f);
    return (u + 0x7fffu + ((u >> 16) & 1u)) >> 16;   // round-to-nearest-even
}
__device__ __forceinline__ float bf16tof(unsigned int h) { return __uint_as_float(h << 16); }
__device__ __forceinline__ float bf16lo(unsigned int v) { return __uint_as_float(v << 16); }
__device__ __forceinline__ float bf16hi(unsigned int v) { return __uint_as_float(v & 0xffff0000u); }

// ---------------------------------------------------------------- K1: hist + weight prep
__global__ __launch_bounds__(256) void hist_kernel(const int* __restrict__ col,
                                                   int* __restrict__ ghist,
                                                   const float* __restrict__ W0,
                                                   const float* __restrict__ W1,
                                                   const float* __restrict__ W2,
                                                   unsigned short* __restrict__ Whi,
                                                   unsigned short* __restrict__ Wlo,
                                                   int E, int nblk, int nbuck) {
    __shared__ int h[256];
    const int t = threadIdx.x, b = blockIdx.x;
    if (b >= nblk) {
        int bb = b - nblk;                            // 0..15
#pragma unroll
        for (int q = 0; q < 12; ++q) {
            int gi = (bb * 12 + q) * 256 + t;         // 0..49151 = 3*16384
            int which = gi >> 14;
            int i = gi & 16383;
            int c = i >> 7, k = i & 127;
            const float* W = (which == 0) ? W0 : (which == 1) ? W1 : W2;
            float w = W[(size_t)k * FEAT + c];
            unsigned int hh = bf16rtn(w);
            size_t off = (size_t)which * 16384 + (size_t)c * FEAT + k;
            Whi[off] = (unsigned short)hh;
            Wlo[off] = (unsigned short)bf16rtn(w - bf16tof(hh));
        }
        return;
    }
    h[t] = 0;
    __syncthreads();
    const int base = b * 4096;
#pragma unroll
    for (int i = 0; i < 16; ++i) {
        int e = base + i * 256 + t;
        if (e < E) atomicAdd(&h[col[e] >> 8], 1);
    }
    __syncthreads();
    if (t < nbuck) ghist[t * nblk + b] = h[t];   // digit-major for the scan
}

// K2: per-256-chunk exclusive scan of ghist -> gsc; RAW chunk sums -> bsum.
__global__ __launch_bounds__(256) void scan_block_kernel(const int* __restrict__ cnt,
                                                         int* __restrict__ out,
                                                         int* __restrict__ bsum, int M) {
    __shared__ int s[256];
    int t = threadIdx.x;
    int i = blockIdx.x * 256 + t;
    int own = (i < M) ? cnt[i] : 0;
    s[t] = own;
    for (int off = 1; off < 256; off <<= 1) {
        __syncthreads();
        int v = (t >= off) ? s[t - off] : 0;
        __syncthreads();
        s[t] += v;
    }
    __syncthreads();
    if (i < M) out[i] = s[t] - own;
    if (t == 255) bsum[blockIdx.x] = s[255];
}

// local 151-element exclusive scan of raw bsum into LDS (redundant per block)
__device__ __forceinline__ void local_bsum_scan(const int* __restrict__ bsum, int snb,
                                                int* __restrict__ sbs, int t) {
    int own = (t < snb) ? bsum[t] : 0;
    sbs[t] = own;
    for (int off = 1; off < 256; off <<= 1) {
        __syncthreads();
        int v = (t >= off) ? sbs[t - off] : 0;
        __syncthreads();
        sbs[t] += v;
    }
    __syncthreads();
    int excl = sbs[t] - own;
    __syncthreads();
    sbs[t] = excl;
    __syncthreads();
}

// K3: scatter into bucket-grouped order.
__global__ __launch_bounds__(256) void scatter1_kernel(const int* __restrict__ row,
                                                       const int* __restrict__ col,
                                                       const float* __restrict__ ew,
                                                       const int* __restrict__ gsc,
                                                       const int* __restrict__ bsum,
                                                       uint2* __restrict__ bedge,
                                                       int E, int nblk, int nbuck, int snb) {
    __shared__ int cur[256];
    __shared__ int sbs[256];
    const int t = threadIdx.x, b = blockIdx.x;
    local_bsum_scan(bsum, snb, sbs, t);
    if (t < nbuck) {
        int idx = t * nblk + b;
        cur[t] = gsc[idx] + sbs[idx >> 8];
    }
    __syncthreads();
    const int base = b * 4096;
#pragma unroll
    for (int i = 0; i < 16; ++i) {
        int e = base + i * 256 + t;
        if (e < E) {
            int c = col[e];
            int slot = atomicAdd(&cur[c >> 8], 1);
            bedge[slot] = make_uint2(((unsigned)c << 16) | (unsigned)row[e],
                                     __float_as_uint(ew[e]));
        }
    }
}

// K4: per-bucket count + weighted degree -> rowptr/dinv; final per-node scatter
// with w*dinv[col] folded in.  (dinv[row] is folded into the GEMM epilogue.)
__global__ __launch_bounds__(256) void bucket_kernel(const uint2* __restrict__ bedge,
                                                     const int* __restrict__ gsc,
                                                     const int* __restrict__ bsum,
                                                     int* __restrict__ rowptr,
                                                     float* __restrict__ dinv,
                                                     uint2* __restrict__ sedge,
                                                     int N, int E, int nblk, int nbuck, int snb) {
    __shared__ int sbs[256];
    __shared__ int lcnt[256];
    __shared__ float lw[256];
    __shared__ int lscan[256];
    __shared__ int lcur[256];
    __shared__ float ldv[256];

    const int d = blockIdx.x, t = threadIdx.x;
    local_bsum_scan(bsum, snb, sbs, t);
    const int i0 = d * nblk;
    const int base = gsc[i0] + sbs[i0 >> 8];
    int end;
    if (d == nbuck - 1) end = E;
    else {
        const int i1 = (d + 1) * nblk;
        end = gsc[i1] + sbs[i1 >> 8];
    }

    lcnt[t] = 0;
    lw[t] = 0.f;
    __syncthreads();
    for (int i = base + t; i < end; i += 256) {
        uint2 p = bedge[i];
        int c = (p.x >> 16) & 255;
        atomicAdd(&lcnt[c], 1);
        atomicAdd(&lw[c], __uint_as_float(p.y));
    }
    __syncthreads();
    int own = lcnt[t];
    lscan[t] = own;
    for (int off = 1; off < 256; off <<= 1) {
        __syncthreads();
        int v = (t >= off) ? lscan[t - off] : 0;
        __syncthreads();
        lscan[t] += v;
    }
    __syncthreads();
    int excl = lscan[t] - own;
    lcur[t] = base + excl;
    float wsum = lw[t];
    float dv = (wsum > 0.f) ? rsqrtf(wsum) : 0.f;
    ldv[t] = dv;
    int node = d * 256 + t;
    if (node < N) {
        rowptr[node] = base + excl;
        dinv[node] = dv;
    }
    if (d == nbuck - 1 && t == 0) rowptr[N] = E;
    __syncthreads();
    for (int i = base + t; i < end; i += 256) {
        uint2 p = bedge[i];
        int c = (p.x >> 16) & 255;
        int slot = atomicAdd(&lcur[c], 1);
        sedge[slot] = make_uint2(p.x & 0xFFFFu,
                                 __float_as_uint(__uint_as_float(p.y) * ldv[c]));
    }
}

// ---------------------------------------------------------------- MFMA GEMM v3 (verified shape)
// grid (782,2) = 1564 blocks. A-fragments from global fp32, split hi/lo
// in-register; 32KB W LDS; epilogue folds dinv[row]. Output is written in
// QUARTER-MAJOR layout: hbq[q][node][16 u32] (64B per feature-quarter) so
// each agg pass gathers from a 3.2MB plane that fits a 4MB per-XCD L2.
__global__ __launch_bounds__(256) void gemm_mfma_kernel(
    const float* __restrict__ X,
    const unsigned short* __restrict__ Wthi, const unsigned short* __restrict__ Wtlo,
    const float* __restrict__ dinv,
    unsigned int* __restrict__ hbq,   // [4][N][16] u32
    int N)
{
    __shared__ unsigned short wh[64 * 128];
    __shared__ unsigned short wl[64 * 128];

    const int tid = threadIdx.x;
    const int r0 = blockIdx.x * 64;
    const int cb = blockIdx.y;       // col half: 0 or 1

#pragma unroll
    for (int it = 0; it < 4; ++it) {
        int idx = it * 256 + tid;
        int c = idx >> 4;
        int k8 = (idx & 15) * 8;
        int sw = k8 ^ ((c & 7) << 3);
        size_t src = (size_t)(cb * 64 + c) * FEAT + k8;
        *(short8*)&wh[c * 128 + sw] = *(const short8*)(Wthi + src);
        *(short8*)&wl[c * 128 + sw] = *(const short8*)(Wtlo + src);
    }
    __syncthreads();

    const int lane = tid & 63;
    const int wv = tid >> 6;
    const int m = lane & 15;
    const int quad = lane >> 4;
    const int arow = wv * 16 + m;
    const int grow = r0 + arow;
    const float* xrow = X + (size_t)grow * FEAT;

    f32x4 acc[4];
#pragma unroll
    for (int ct = 0; ct < 4; ++ct) acc[ct] = (f32x4){0.f, 0.f, 0.f, 0.f};

#pragma unroll
    for (int kt = 0; kt < 4; ++kt) {
        const int k0 = kt * 32 + quad * 8;
        float4 va = make_float4(0.f, 0.f, 0.f, 0.f);
        float4 vb = make_float4(0.f, 0.f, 0.f, 0.f);
        if (grow < N) {
            va = *(const float4*)(xrow + k0);
            vb = *(const float4*)(xrow + k0 + 4);
        }
        unsigned int h0 = bf16rtn(va.x), h1 = bf16rtn(va.y);
        unsigned int h2 = bf16rtn(va.z), h3 = bf16rtn(va.w);
        unsigned int h4 = bf16rtn(vb.x), h5 = bf16rtn(vb.y);
        unsigned int h6 = bf16rtn(vb.z), h7 = bf16rtn(vb.w);
        short8 ah, al;
        ah[0] = (short)h0; ah[1] = (short)h1; ah[2] = (short)h2; ah[3] = (short)h3;
        ah[4] = (short)h4; ah[5] = (short)h5; ah[6] = (short)h6; ah[7] = (short)h7;
        al[0] = (short)bf16rtn(va.x - bf16tof(h0));
        al[1] = (short)bf16rtn(va.y - bf16tof(h1));
        al[2] = (short)bf16rtn(va.z - bf16tof(h2));
        al[3] = (short)bf16rtn(va.w - bf16tof(h3));
        al[4] = (short)bf16rtn(vb.x - bf16tof(h4));
        al[5] = (short)bf16rtn(vb.y - bf16tof(h5));
        al[6] = (short)bf16rtn(vb.z - bf16tof(h6));
        al[7] = (short)bf16rtn(vb.w - bf16tof(h7));
#pragma unroll
        for (int ct = 0; ct < 4; ++ct) {
            int bc = ct * 16 + m;
            int bw = k0 ^ ((bc & 7) << 3);
            short8 bh = *(const short8*)&wh[bc * 128 + bw];
            short8 bl = *(const short8*)&wl[bc * 128 + bw];
            acc[ct] = __builtin_amdgcn_mfma_f32_16x16x32_bf16(ah, bh, acc[ct], 0, 0, 0);
            acc[ct] = __builtin_amdgcn_mfma_f32_16x16x32_bf16(ah, bl, acc[ct], 0, 0, 0);
            acc[ct] = __builtin_amdgcn_mfma_f32_16x16x32_bf16(al, bh, acc[ct], 0, 0, 0);
        }
    }

    const int rbase = wv * 16 + quad * 4;
    const int grb = r0 + rbase;
    float dv0, dv1, dv2, dv3;
    if (grb + 3 < N) {
        float4 d4 = *(const float4*)(dinv + grb);
        dv0 = d4.x; dv1 = d4.y; dv2 = d4.z; dv3 = d4.w;
    } else {
        dv0 = (grb + 0 < N) ? dinv[grb + 0] : 0.f;
        dv1 = (grb + 1 < N) ? dinv[grb + 1] : 0.f;
        dv2 = (grb + 2 < N) ? dinv[grb + 2] : 0.f;
        dv3 = (grb + 3 < N) ? dinv[grb + 3] : 0.f;
    }

    __syncthreads();                 // all waves done reading wh -> reuse as epilogue buf
    unsigned short* cl = wh;         // 64*72*2B = 9.2KB, fits
#pragma unroll
    for (int ct = 0; ct < 4; ++ct) {
        cl[(rbase + 0) * 72 + ct * 16 + m] = (unsigned short)bf16rtn(acc[ct][0] * dv0);
        cl[(rbase + 1) * 72 + ct * 16 + m] = (unsigned short)bf16rtn(acc[ct][1] * dv1);
        cl[(rbase + 2) * 72 + ct * 16 + m] = (unsigned short)bf16rtn(acc[ct][2] * dv2);
        cl[(rbase + 3) * 72 + ct * 16 + m] = (unsigned short)bf16rtn(acc[ct][3] * dv3);
    }
    __syncthreads();
#pragma unroll
    for (int it = 0; it < 2; ++it) {
        int idx = it * 256 + tid;
        int r = idx >> 3;
        int c4 = (idx & 7) * 4;          // u32 col within half: 0..28
        int gr = r0 + r;
        if (gr < N) {
            uint4 pv = *(const uint4*)&cl[r * 72 + c4 * 2];
            int col_u = cb * 32 + c4;    // 0..63 (u32 col in the full row)
            int q = col_u >> 4;          // feature quarter
            int wq = col_u & 15;         // u32 within quarter (multiple of 4)
            *(uint4*)(hbq + ((size_t)q * N + gr) * 16 + wq) = pv;
        }
    }
}

// ---------------------------------------------------------------- CSR aggregation v11
// Quarter-split for L2 residency: grid = 4 quarter-phases x 3125 node-blocks
// (quarter-major dispatch order keeps one 3.2MB hbq plane hot per phase;
// 3.2MB < 4MB per-XCD L2 so the 16x edge reuse hits own-L2 instead of L3).
// Subgroup = 16 lanes/node reshaped as 4 edge-slots x 4 feature-lanes:
// 4 adjacent lanes read one contiguous 64B quarter-row (coalesced), meta is
// 4-way same-address broadcast. 16-edge chunks (1 epoch for d<=16, 57% of
// nodes). 2x shfl_xor reduce over edge-slots; es==0 lanes store fp32.
template <int MODE>   // 0: +relu -> outX (layers 1,2); 1: no relu -> outX (layer 3)
__global__ __launch_bounds__(256) void agg_kernel(
    const int* __restrict__ rowptr, const uint2* __restrict__ sedge,
    const unsigned int* __restrict__ hbq,   // [4][N][16] u32
    const float* __restrict__ bias,
    float* __restrict__ outX, int N, int nb16)
{
    const int q  = blockIdx.x / nb16;
    const int nb = blockIdx.x - q * nb16;
    const int node = nb * 16 + (threadIdx.x >> 4);
    if (node >= N) return;
    const int j  = threadIdx.x & 15;
    const int fl = j & 3;        // feature-lane: 16B = 8 features of the quarter
    const int es = j >> 2;       // edge-slot 0..3
    const int s = rowptr[node];
    const int e = rowptr[node + 1];
    const unsigned int* hq = hbq + (size_t)q * N * 16;

    float a0 = 0.f, a1 = 0.f, a2 = 0.f, a3 = 0.f;
    float a4 = 0.f, a5 = 0.f, a6 = 0.f, a7 = 0.f;

    for (int gb = s; gb < e; gb += 16) {
        const int e0 = gb + es * 4 + 0;
        const int e1 = gb + es * 4 + 1;
        const int e2 = gb + es * 4 + 2;
        const int e3 = gb + es * 4 + 3;
        const uint2 z = make_uint2(0u, 0u);
        const uint4 z4 = make_uint4(0u, 0u, 0u, 0u);
        uint2 m0 = (e0 < e) ? sedge[e0] : z;
        uint2 m1 = (e1 < e) ? sedge[e1] : z;
        uint2 m2 = (e2 < e) ? sedge[e2] : z;
        uint2 m3 = (e3 < e) ? sedge[e3] : z;
        uint4 v0 = (e0 < e) ? *(const uint4*)(hq + (size_t)m0.x * 16 + fl * 4) : z4;
        uint4 v1 = (e1 < e) ? *(const uint4*)(hq + (size_t)m1.x * 16 + fl * 4) : z4;
        uint4 v2 = (e2 < e) ? *(const uint4*)(hq + (size_t)m2.x * 16 + fl * 4) : z4;
        uint4 v3 = (e3 < e) ? *(const uint4*)(hq + (size_t)m3.x * 16 + fl * 4) : z4;
        float w0 = __uint_as_float(m0.y), w1 = __uint_as_float(m1.y);
        float w2 = __uint_as_float(m2.y), w3 = __uint_as_float(m3.y);
        a0 = fmaf(w0, bf16lo(v0.x), a0); a1 = fmaf(w0, bf16hi(v0.x), a1);
        a2 = fmaf(w0, bf16lo(v0.y), a2); a3 = fmaf(w0, bf16hi(v0.y), a3);
        a4 = fmaf(w0, bf16lo(v0.z), a4); a5 = fmaf(w0, bf16hi(v0.z), a5);
        a6 = fmaf(w0, bf16lo(v0.w), a6); a7 = fmaf(w0, bf16hi(v0.w), a7);
        a0 = fmaf(w1, bf16lo(v1.x), a0); a1 = fmaf(w1, bf16hi(v1.x), a1);
        a2 = fmaf(w1, bf16lo(v1.y), a2); a3 = fmaf(w1, bf16hi(v1.y), a3);
        a4 = fmaf(w1, bf16lo(v1.z), a4); a5 = fmaf(w1, bf16hi(v1.z), a5);
        a6 = fmaf(w1, bf16lo(v1.w), a6); a7 = fmaf(w1, bf16hi(v1.w), a7);
        a0 = fmaf(w2, bf16lo(v2.x), a0); a1 = fmaf(w2, bf16hi(v2.x), a1);
        a2 = fmaf(w2, bf16lo(v2.y), a2); a3 = fmaf(w2, bf16hi(v2.y), a3);
        a4 = fmaf(w2, bf16lo(v2.z), a4); a5 = fmaf(w2, bf16hi(v2.z), a5);
        a6 = fmaf(w2, bf16lo(v2.w), a6); a7 = fmaf(w2, bf16hi(v2.w), a7);
        a0 = fmaf(w3, bf16lo(v3.x), a0); a1 = fmaf(w3, bf16hi(v3.x), a1);
        a2 = fmaf(w3, bf16lo(v3.y), a2); a3 = fmaf(w3, bf16hi(v3.y), a3);
        a4 = fmaf(w3, bf16lo(v3.z), a4); a5 = fmaf(w3, bf16hi(v3.z), a5);
        a6 = fmaf(w3, bf16lo(v3.w), a6); a7 = fmaf(w3, bf16hi(v3.w), a7);
    }

    // combine the 4 edge-slots (same feature set across es; xor 4 and 8 flip es bits)
    a0 += __shfl_xor(a0, 4); a0 += __shfl_xor(a0, 8);
    a1 += __shfl_xor(a1, 4); a1 += __shfl_xor(a1, 8);
    a2 += __shfl_xor(a2, 4); a2 += __shfl_xor(a2, 8);
    a3 += __shfl_xor(a3, 4); a3 += __shfl_xor(a3, 8);
    a4 += __shfl_xor(a4, 4); a4 += __shfl_xor(a4, 8);
    a5 += __shfl_xor(a5, 4); a5 += __shfl_xor(a5, 8);
    a6 += __shfl_xor(a6, 4); a6 += __shfl_xor(a6, 8);
    a7 += __shfl_xor(a7, 4); a7 += __shfl_xor(a7, 8);

    if (es == 0) {
        float4 bv0 = ((const float4*)bias)[q * 8 + fl * 2];
        float4 bv1 = ((const float4*)bias)[q * 8 + fl * 2 + 1];
        a0 += bv0.x; a1 += bv0.y; a2 += bv0.z; a3 += bv0.w;
        a4 += bv1.x; a5 += bv1.y; a6 += bv1.z; a7 += bv1.w;
        if (MODE == 0) {
            a0 = fmaxf(a0, 0.f); a1 = fmaxf(a1, 0.f);
            a2 = fmaxf(a2, 0.f); a3 = fmaxf(a3, 0.f);
            a4 = fmaxf(a4, 0.f); a5 = fmaxf(a5, 0.f);
            a6 = fmaxf(a6, 0.f); a7 = fmaxf(a7, 0.f);
        }
        float* dst = outX + (size_t)node * FEAT + q * 32 + fl * 8;
        *(float4*)(dst)     = make_float4(a0, a1, a2, a3);
        *(float4*)(dst + 4) = make_float4(a4, a5, a6, a7);
    }
}

// ---------------------------------------------------------------- readout v3
__global__ __launch_bounds__(256) void readout_kernel(const float* __restrict__ h,
                                                      const int* __restrict__ batch,
                                                      float* __restrict__ ro, int N) {
    __shared__ float part[128];
    const int g = blockIdx.x;
    const int j = threadIdx.x & 127;
    const int half = threadIdx.x >> 7;
    int lo = 0, hi = N;
    while (lo < hi) { int mid = (lo + hi) >> 1; if (batch[mid] < g) lo = mid + 1; else hi = mid; }
    int lo2 = lo, hi2 = N;
    while (lo2 < hi2) { int mid = (lo2 + hi2) >> 1; if (batch[mid] < g + 1) lo2 = mid + 1; else hi2 = mid; }

    float s0 = 0.f, s1 = 0.f;
    int n = lo + half;
    for (; n + 2 < lo2; n += 4) {
        s0 += h[(size_t)n * FEAT + j];
        s1 += h[(size_t)(n + 2) * FEAT + j];
    }
    if (n < lo2) s0 += h[(size_t)n * FEAT + j];
    float s = s0 + s1;
    if (half == 1) part[j] = s;
    __syncthreads();
    if (half == 0) ro[(size_t)g * FEAT + j] = s + part[j];
}

// ---------------------------------------------------------------- launch
static inline size_t align256(size_t x) { return (x + 255) & ~(size_t)255; }

extern "C" void kernel_launch(void* const* d_in, const int* in_sizes, int n_in,
                              void* d_out, int out_size, void* d_ws, size_t ws_size,
                              hipStream_t stream) {
    const float* gx    = (const float*)d_in[0];
    const int*   ei    = (const int*)d_in[1];
    const int*   batch = (const int*)d_in[2];
    const float* ew    = (const float*)d_in[3];
    const float* W1 = (const float*)d_in[4];
    const float* b1 = (const float*)d_in[5];
    const float* W2 = (const float*)d_in[6];
    const float* b2 = (const float*)d_in[7];
    const float* W3 = (const float*)d_in[8];
    const float* b3 = (const float*)d_in[9];

    const int N = in_sizes[0] / FEAT;            // 50000
    const int E = in_sizes[3];                   // 800000
    const int G = (out_size - N * FEAT) / FEAT;  // 256

    const int* row = ei;
    const int* col = ei + E;

    const int nbuck = (N + 255) >> 8;            // 196
    const int nblk  = (E + 4095) >> 12;          // 196
    const int M     = nbuck * nblk;              // 38416
    const int snb   = (M + 255) / 256;           // 151

    // ---- workspace layout
    char* ws = (char*)d_ws;
    int*   rowptr = (int*)ws;         ws += align256((size_t)(N + 1) * 4);
    float* dinv   = (float*)ws;       ws += align256((size_t)N * 4);
    int*   ghist  = (int*)ws;         ws += align256((size_t)M * 4);
    int*   gsc    = (int*)ws;         ws += align256((size_t)M * 4);
    int*   bsum   = (int*)ws;         ws += align256(256 * 4);
    uint2* bedge  = (uint2*)ws;       ws += align256((size_t)E * 8);
    uint2* sedge  = (uint2*)ws;       ws += align256((size_t)E * 8);
    unsigned int* hbq = (unsigned int*)ws;  ws += align256((size_t)N * 64 * 4);
    float* bufX   = (float*)ws;       ws += align256((size_t)N * FEAT * 4);
    unsigned short* Wh = (unsigned short*)ws; ws += align256((size_t)3 * 16384 * 2);
    unsigned short* Wl = (unsigned short*)ws; ws += align256((size_t)3 * 16384 * 2);

    float* h_out = (float*)d_out;
    float* ro    = h_out + (size_t)N * FEAT;

    // ---- bucket-sorted CSR build + weight prep (4 launches, no global sync)
    hist_kernel<<<nblk + 16, 256, 0, stream>>>(col, ghist, W1, W2, W3, Wh, Wl, E, nblk, nbuck);
    scan_block_kernel<<<snb, 256, 0, stream>>>(ghist, gsc, bsum, M);
    scatter1_kernel<<<nblk, 256, 0, stream>>>(row, col, ew, gsc, bsum, bedge, E, nblk, nbuck, snb);
    bucket_kernel<<<nbuck, 256, 0, stream>>>(bedge, gsc, bsum, rowptr, dinv, sedge, N, E, nblk, nbuck, snb);

    dim3 ggrid((N + 63) / 64, 2);
    const int nb16 = (N + 15) / 16;              // 3125
    const int ablocks = 4 * nb16;                // 12500 (quarter-major order)

    // ---- layer 1
    gemm_mfma_kernel<<<ggrid, 256, 0, stream>>>(gx, Wh, Wl, dinv, hbq, N);
    agg_kernel<0><<<ablocks, 256, 0, stream>>>(rowptr, sedge, hbq, b1, bufX, N, nb16);
    // ---- layer 2
    gemm_mfma_kernel<<<ggrid, 256, 0, stream>>>(bufX, Wh + 16384, Wl + 16384, dinv, hbq, N);
    agg_kernel<0><<<ablocks, 256, 0, stream>>>(rowptr, sedge, hbq, b2, bufX, N, nb16);
    // ---- layer 3
    gemm_mfma_kernel<<<ggrid, 256, 0, stream>>>(bufX, Wh + 32768, Wl + 32768, dinv, hbq, N);
    agg_kernel<1><<<ablocks, 256, 0, stream>>>(rowptr, sedge, hbq, b3, h_out, N, nb16);
    // ---- readout: one block per graph, atomic-free
    readout_kernel<<<G, 256, 0, stream>>>(h_out, batch, ro, N);
}

// Round 10
// 310.424 us; speedup vs baseline: 1.3891x; 1.3891x over previous
//
#include <hip/hip_runtime.h>

#define FEAT 128
#define EPB 1024   // edges per hist/scatter block

typedef __attribute__((ext_vector_type(8))) short short8;   // 8 bf16 = 4 VGPRs
typedef __attribute__((ext_vector_type(4))) float f32x4;

__device__ __forceinline__ unsigned int bf16rtn(float f) {
    unsigned int u = __float_as_uint(f);
    return (u + 0x7fffu + ((u >> 16) & 1u)) >> 16;   // round-to-nearest-even
}
__device__ __forceinline__ float bf16tof(unsigned int h) { return __uint_as_float(h << 16); }
__device__ __forceinline__ float bf16lo(unsigned int v) { return __uint_as_float(v << 16); }
__device__ __forceinline__ float bf16hi(unsigned int v) { return __uint_as_float(v & 0xffff0000u); }

// ---------------------------------------------------------------- K1: hist + weight prep
// blocks 0..nblk-1: 1024-edge LDS histogram (782 blocks -> 3 blocks/CU).
// blocks nblk..nblk+15: all 3 weights -> transposed bf16 hi/lo planes.
__global__ __launch_bounds__(256) void hist_kernel(const int* __restrict__ col,
                                                   int* __restrict__ ghist,
                                                   const float* __restrict__ W0,
                                                   const float* __restrict__ W1,
                                                   const float* __restrict__ W2,
                                                   unsigned short* __restrict__ Whi,
                                                   unsigned short* __restrict__ Wlo,
                                                   int E, int nblk, int nbuck) {
    __shared__ int h[256];
    const int t = threadIdx.x, b = blockIdx.x;
    if (b >= nblk) {
        int bb = b - nblk;                            // 0..15
#pragma unroll
        for (int q = 0; q < 12; ++q) {
            int gi = (bb * 12 + q) * 256 + t;         // 0..49151 = 3*16384
            int which = gi >> 14;
            int i = gi & 16383;
            int c = i >> 7, k = i & 127;
            const float* W = (which == 0) ? W0 : (which == 1) ? W1 : W2;
            float w = W[(size_t)k * FEAT + c];
            unsigned int hh = bf16rtn(w);
            size_t off = (size_t)which * 16384 + (size_t)c * FEAT + k;
            Whi[off] = (unsigned short)hh;
            Wlo[off] = (unsigned short)bf16rtn(w - bf16tof(hh));
        }
        return;
    }
    h[t] = 0;
    __syncthreads();
    const int base = b * EPB;
#pragma unroll
    for (int i = 0; i < 4; ++i) {
        int e = base + i * 256 + t;
        if (e < E) atomicAdd(&h[col[e] >> 8], 1);
    }
    __syncthreads();
    if (t < nbuck) ghist[t * nblk + b] = h[t];   // digit-major for the scan
}

// K2: per-256-chunk exclusive scan of ghist -> gsc; raw chunk sums -> bsum.
__global__ __launch_bounds__(256) void scan_block_kernel(const int* __restrict__ cnt,
                                                         int* __restrict__ out,
                                                         int* __restrict__ bsum, int M) {
    __shared__ int s[256];
    int t = threadIdx.x;
    int i = blockIdx.x * 256 + t;
    int own = (i < M) ? cnt[i] : 0;
    s[t] = own;
    for (int off = 1; off < 256; off <<= 1) {
        __syncthreads();
        int v = (t >= off) ? s[t - off] : 0;
        __syncthreads();
        s[t] += v;
    }
    __syncthreads();
    if (i < M) out[i] = s[t] - own;
    if (t == 255) bsum[blockIdx.x] = s[255];
}

// K2b: exclusive scan of bsum in place (nb <= 1024; 4 elements/thread)
__global__ __launch_bounds__(256) void scan_bsum_kernel(int* __restrict__ bsum, int nb) {
    __shared__ int s[256];
    int t = threadIdx.x;
    int i0 = 4 * t;
    int v0 = (i0 + 0 < nb) ? bsum[i0 + 0] : 0;
    int v1 = (i0 + 1 < nb) ? bsum[i0 + 1] : 0;
    int v2 = (i0 + 2 < nb) ? bsum[i0 + 2] : 0;
    int v3 = (i0 + 3 < nb) ? bsum[i0 + 3] : 0;
    int sum = v0 + v1 + v2 + v3;
    s[t] = sum;
    for (int off = 1; off < 256; off <<= 1) {
        __syncthreads();
        int v = (t >= off) ? s[t - off] : 0;
        __syncthreads();
        s[t] += v;
    }
    __syncthreads();
    int excl = s[t] - sum;
    if (i0 + 0 < nb) bsum[i0 + 0] = excl;
    if (i0 + 1 < nb) bsum[i0 + 1] = excl + v0;
    if (i0 + 2 < nb) bsum[i0 + 2] = excl + v0 + v1;
    if (i0 + 3 < nb) bsum[i0 + 3] = excl + v0 + v1 + v2;
}

// K3: scatter into bucket-grouped order (782 blocks; nt stores skip
// write-allocate line fetches on the random 8B scatter).
__global__ __launch_bounds__(256) void scatter1_kernel(const int* __restrict__ row,
                                                       const int* __restrict__ col,
                                                       const float* __restrict__ ew,
                                                       const int* __restrict__ gsc,
                                                       const int* __restrict__ bsum,
                                                       uint2* __restrict__ bedge,
                                                       int E, int nblk, int nbuck) {
    __shared__ int cur[256];
    const int t = threadIdx.x, b = blockIdx.x;
    if (t < nbuck) {
        int idx = t * nblk + b;
        cur[t] = gsc[idx] + bsum[idx >> 8];
    }
    __syncthreads();
    const int base = b * EPB;
#pragma unroll
    for (int i = 0; i < 4; ++i) {
        int e = base + i * 256 + t;
        if (e < E) {
            int c = col[e];
            int slot = atomicAdd(&cur[c >> 8], 1);
            unsigned long long pv =
                ((unsigned long long)__float_as_uint(ew[e]) << 32) |
                (((unsigned)c << 16) | (unsigned)row[e]);
            __builtin_nontemporal_store(pv, (unsigned long long*)(bedge + slot));
        }
    }
}

// K4: per-bucket (1024 threads: 4 edge-iters/pass instead of 16) count +
// weighted degree -> rowptr/dinv; final per-node scatter with w*dinv[col]
// folded in (nt stores). dinv[row] is folded into the GEMM epilogue.
__global__ __launch_bounds__(1024) void bucket_kernel(const uint2* __restrict__ bedge,
                                                      const int* __restrict__ gsc,
                                                      const int* __restrict__ bsum,
                                                      int* __restrict__ rowptr,
                                                      float* __restrict__ dinv,
                                                      uint2* __restrict__ sedge,
                                                      int N, int E, int nblk, int nbuck) {
    __shared__ int lcnt[256];
    __shared__ float lw[256];
    __shared__ int lscan[256];
    __shared__ int lcur[256];
    __shared__ float ldv[256];

    const int d = blockIdx.x, t = threadIdx.x;
    const int i0 = d * nblk;
    const int base = gsc[i0] + bsum[i0 >> 8];
    int end;
    if (d == nbuck - 1) end = E;
    else {
        const int i1 = (d + 1) * nblk;
        end = gsc[i1] + bsum[i1 >> 8];
    }

    if (t < 256) { lcnt[t] = 0; lw[t] = 0.f; }
    __syncthreads();
    for (int i = base + t; i < end; i += 1024) {
        uint2 p = bedge[i];
        int c = (p.x >> 16) & 255;
        atomicAdd(&lcnt[c], 1);
        atomicAdd(&lw[c], __uint_as_float(p.y));
    }
    __syncthreads();
    int own = 0;
    if (t < 256) { own = lcnt[t]; lscan[t] = own; }
    for (int off = 1; off < 256; off <<= 1) {
        __syncthreads();
        int v = (t >= off && t < 256) ? lscan[t - off] : 0;
        __syncthreads();
        if (t < 256) lscan[t] += v;
    }
    __syncthreads();
    if (t < 256) {
        int excl = lscan[t] - own;
        lcur[t] = base + excl;
        float wsum = lw[t];
        float dv = (wsum > 0.f) ? rsqrtf(wsum) : 0.f;
        ldv[t] = dv;
        int node = d * 256 + t;
        if (node < N) {
            rowptr[node] = base + excl;
            dinv[node] = dv;
        }
        if (d == nbuck - 1 && t == 0) rowptr[N] = E;
    }
    __syncthreads();
    for (int i = base + t; i < end; i += 1024) {
        uint2 p = bedge[i];
        int c = (p.x >> 16) & 255;
        int slot = atomicAdd(&lcur[c], 1);
        unsigned long long pv =
            ((unsigned long long)__float_as_uint(__uint_as_float(p.y) * ldv[c]) << 32) |
            (p.x & 0xFFFFu);
        __builtin_nontemporal_store(pv, (unsigned long long*)(sedge + slot));
    }
}

// ---------------------------------------------------------------- MFMA GEMM v3 (verified, ~12us)
// grid (782,2) = 1564 blocks. A-fragments from global fp32, split hi/lo
// in-register; 32KB W LDS; epilogue folds dinv[row].
__global__ __launch_bounds__(256) void gemm_mfma_kernel(
    const float* __restrict__ X,
    const unsigned short* __restrict__ Wthi, const unsigned short* __restrict__ Wtlo,
    const float* __restrict__ dinv,
    unsigned int* __restrict__ hb,   // N x 64 packed bf16 out
    int N)
{
    __shared__ unsigned short wh[64 * 128];
    __shared__ unsigned short wl[64 * 128];

    const int tid = threadIdx.x;
    const int r0 = blockIdx.x * 64;
    const int cb = blockIdx.y;       // col half: 0 or 1

#pragma unroll
    for (int it = 0; it < 4; ++it) {
        int idx = it * 256 + tid;
        int c = idx >> 4;
        int k8 = (idx & 15) * 8;
        int sw = k8 ^ ((c & 7) << 3);
        size_t src = (size_t)(cb * 64 + c) * FEAT + k8;
        *(short8*)&wh[c * 128 + sw] = *(const short8*)(Wthi + src);
        *(short8*)&wl[c * 128 + sw] = *(const short8*)(Wtlo + src);
    }
    __syncthreads();

    const int lane = tid & 63;
    const int wv = tid >> 6;
    const int m = lane & 15;
    const int quad = lane >> 4;
    const int arow = wv * 16 + m;
    const int grow = r0 + arow;
    const float* xrow = X + (size_t)grow * FEAT;

    f32x4 acc[4];
#pragma unroll
    for (int ct = 0; ct < 4; ++ct) acc[ct] = (f32x4){0.f, 0.f, 0.f, 0.f};

#pragma unroll
    for (int kt = 0; kt < 4; ++kt) {
        const int k0 = kt * 32 + quad * 8;
        float4 va = make_float4(0.f, 0.f, 0.f, 0.f);
        float4 vb = make_float4(0.f, 0.f, 0.f, 0.f);
        if (grow < N) {
            va = *(const float4*)(xrow + k0);
            vb = *(const float4*)(xrow + k0 + 4);
        }
        unsigned int h0 = bf16rtn(va.x), h1 = bf16rtn(va.y);
        unsigned int h2 = bf16rtn(va.z), h3 = bf16rtn(va.w);
        unsigned int h4 = bf16rtn(vb.x), h5 = bf16rtn(vb.y);
        unsigned int h6 = bf16rtn(vb.z), h7 = bf16rtn(vb.w);
        short8 ah, al;
        ah[0] = (short)h0; ah[1] = (short)h1; ah[2] = (short)h2; ah[3] = (short)h3;
        ah[4] = (short)h4; ah[5] = (short)h5; ah[6] = (short)h6; ah[7] = (short)h7;
        al[0] = (short)bf16rtn(va.x - bf16tof(h0));
        al[1] = (short)bf16rtn(va.y - bf16tof(h1));
        al[2] = (short)bf16rtn(va.z - bf16tof(h2));
        al[3] = (short)bf16rtn(va.w - bf16tof(h3));
        al[4] = (short)bf16rtn(vb.x - bf16tof(h4));
        al[5] = (short)bf16rtn(vb.y - bf16tof(h5));
        al[6] = (short)bf16rtn(vb.z - bf16tof(h6));
        al[7] = (short)bf16rtn(vb.w - bf16tof(h7));
#pragma unroll
        for (int ct = 0; ct < 4; ++ct) {
            int bc = ct * 16 + m;
            int bw = k0 ^ ((bc & 7) << 3);
            short8 bh = *(const short8*)&wh[bc * 128 + bw];
            short8 bl = *(const short8*)&wl[bc * 128 + bw];
            acc[ct] = __builtin_amdgcn_mfma_f32_16x16x32_bf16(ah, bh, acc[ct], 0, 0, 0);
            acc[ct] = __builtin_amdgcn_mfma_f32_16x16x32_bf16(ah, bl, acc[ct], 0, 0, 0);
            acc[ct] = __builtin_amdgcn_mfma_f32_16x16x32_bf16(al, bh, acc[ct], 0, 0, 0);
        }
    }

    const int rbase = wv * 16 + quad * 4;
    const int grb = r0 + rbase;
    float dv0, dv1, dv2, dv3;
    if (grb + 3 < N) {
        float4 d4 = *(const float4*)(dinv + grb);
        dv0 = d4.x; dv1 = d4.y; dv2 = d4.z; dv3 = d4.w;
    } else {
        dv0 = (grb + 0 < N) ? dinv[grb + 0] : 0.f;
        dv1 = (grb + 1 < N) ? dinv[grb + 1] : 0.f;
        dv2 = (grb + 2 < N) ? dinv[grb + 2] : 0.f;
        dv3 = (grb + 3 < N) ? dinv[grb + 3] : 0.f;
    }

    __syncthreads();                 // all waves done reading wh -> reuse as epilogue buf
    unsigned short* cl = wh;         // 64*72*2B = 9.2KB, fits
#pragma unroll
    for (int ct = 0; ct < 4; ++ct) {
        cl[(rbase + 0) * 72 + ct * 16 + m] = (unsigned short)bf16rtn(acc[ct][0] * dv0);
        cl[(rbase + 1) * 72 + ct * 16 + m] = (unsigned short)bf16rtn(acc[ct][1] * dv1);
        cl[(rbase + 2) * 72 + ct * 16 + m] = (unsigned short)bf16rtn(acc[ct][2] * dv2);
        cl[(rbase + 3) * 72 + ct * 16 + m] = (unsigned short)bf16rtn(acc[ct][3] * dv3);
    }
    __syncthreads();
#pragma unroll
    for (int it = 0; it < 2; ++it) {
        int idx = it * 256 + tid;
        int r = idx >> 3;
        int c4 = (idx & 7) * 4;
        int gr = r0 + r;
        if (gr < N) {
            uint4 pv = *(const uint4*)&cl[r * 72 + c4 * 2];
            *(uint4*)(hb + (size_t)gr * 64 + cb * 32 + c4) = pv;
        }
    }
}

// ---------------------------------------------------------------- CSR aggregation v8 (verified, ~38us)
// One 16-lane subgroup per node (16 nodes/block). Lane owns 8 features
// (uint4 = 16B of the 256B row). 8 row-gathers in flight; no reduction.
template <int RELU>
__global__ __launch_bounds__(256) void agg_kernel(
    const int* __restrict__ rowptr, const uint2* __restrict__ sedge,
    const uint4* __restrict__ hb4,   // N x 16 uint4 rows (256B packed bf16)
    const float* __restrict__ bias,
    float* __restrict__ outX, int N)
{
    const int node = blockIdx.x * 16 + (threadIdx.x >> 4);
    if (node >= N) return;
    const int j = threadIdx.x & 15;
    const int s = rowptr[node];
    const int e = rowptr[node + 1];

    float a0 = 0.f, a1 = 0.f, a2 = 0.f, a3 = 0.f;
    float a4 = 0.f, a5 = 0.f, a6 = 0.f, a7 = 0.f;

    for (int gb = s; gb < e; gb += 8) {
        uint2 m0, m1, m2, m3, m4, m5, m6, m7;
        if (gb + 8 <= e) {
            m0 = sedge[gb + 0]; m1 = sedge[gb + 1];
            m2 = sedge[gb + 2]; m3 = sedge[gb + 3];
            m4 = sedge[gb + 4]; m5 = sedge[gb + 5];
            m6 = sedge[gb + 6]; m7 = sedge[gb + 7];
        } else {
            const uint2 z = make_uint2(0u, 0u);
            m0 = (gb + 0 < e) ? sedge[gb + 0] : z;
            m1 = (gb + 1 < e) ? sedge[gb + 1] : z;
            m2 = (gb + 2 < e) ? sedge[gb + 2] : z;
            m3 = (gb + 3 < e) ? sedge[gb + 3] : z;
            m4 = (gb + 4 < e) ? sedge[gb + 4] : z;
            m5 = (gb + 5 < e) ? sedge[gb + 5] : z;
            m6 = (gb + 6 < e) ? sedge[gb + 6] : z;
            m7 = (gb + 7 < e) ? sedge[gb + 7] : z;
        }
        uint4 v0 = hb4[(size_t)m0.x * 16 + j];
        uint4 v1 = hb4[(size_t)m1.x * 16 + j];
        uint4 v2 = hb4[(size_t)m2.x * 16 + j];
        uint4 v3 = hb4[(size_t)m3.x * 16 + j];
        uint4 v4 = hb4[(size_t)m4.x * 16 + j];
        uint4 v5 = hb4[(size_t)m5.x * 16 + j];
        uint4 v6 = hb4[(size_t)m6.x * 16 + j];
        uint4 v7 = hb4[(size_t)m7.x * 16 + j];
        float w0 = __uint_as_float(m0.y), w1 = __uint_as_float(m1.y);
        float w2 = __uint_as_float(m2.y), w3 = __uint_as_float(m3.y);
        float w4 = __uint_as_float(m4.y), w5 = __uint_as_float(m5.y);
        float w6 = __uint_as_float(m6.y), w7 = __uint_as_float(m7.y);
        a0 = fmaf(w0, bf16lo(v0.x), a0); a1 = fmaf(w0, bf16hi(v0.x), a1);
        a2 = fmaf(w0, bf16lo(v0.y), a2); a3 = fmaf(w0, bf16hi(v0.y), a3);
        a4 = fmaf(w0, bf16lo(v0.z), a4); a5 = fmaf(w0, bf16hi(v0.z), a5);
        a6 = fmaf(w0, bf16lo(v0.w), a6); a7 = fmaf(w0, bf16hi(v0.w), a7);
        a0 = fmaf(w1, bf16lo(v1.x), a0); a1 = fmaf(w1, bf16hi(v1.x), a1);
        a2 = fmaf(w1, bf16lo(v1.y), a2); a3 = fmaf(w1, bf16hi(v1.y), a3);
        a4 = fmaf(w1, bf16lo(v1.z), a4); a5 = fmaf(w1, bf16hi(v1.z), a5);
        a6 = fmaf(w1, bf16lo(v1.w), a6); a7 = fmaf(w1, bf16hi(v1.w), a7);
        a0 = fmaf(w2, bf16lo(v2.x), a0); a1 = fmaf(w2, bf16hi(v2.x), a1);
        a2 = fmaf(w2, bf16lo(v2.y), a2); a3 = fmaf(w2, bf16hi(v2.y), a3);
        a4 = fmaf(w2, bf16lo(v2.z), a4); a5 = fmaf(w2, bf16hi(v2.z), a5);
        a6 = fmaf(w2, bf16lo(v2.w), a6); a7 = fmaf(w2, bf16hi(v2.w), a7);
        a0 = fmaf(w3, bf16lo(v3.x), a0); a1 = fmaf(w3, bf16hi(v3.x), a1);
        a2 = fmaf(w3, bf16lo(v3.y), a2); a3 = fmaf(w3, bf16hi(v3.y), a3);
        a4 = fmaf(w3, bf16lo(v3.z), a4); a5 = fmaf(w3, bf16hi(v3.z), a5);
        a6 = fmaf(w3, bf16lo(v3.w), a6); a7 = fmaf(w3, bf16hi(v3.w), a7);
        a0 = fmaf(w4, bf16lo(v4.x), a0); a1 = fmaf(w4, bf16hi(v4.x), a1);
        a2 = fmaf(w4, bf16lo(v4.y), a2); a3 = fmaf(w4, bf16hi(v4.y), a3);
        a4 = fmaf(w4, bf16lo(v4.z), a4); a5 = fmaf(w4, bf16hi(v4.z), a5);
        a6 = fmaf(w4, bf16lo(v4.w), a6); a7 = fmaf(w4, bf16hi(v4.w), a7);
        a0 = fmaf(w5, bf16lo(v5.x), a0); a1 = fmaf(w5, bf16hi(v5.x), a1);
        a2 = fmaf(w5, bf16lo(v5.y), a2); a3 = fmaf(w5, bf16hi(v5.y), a3);
        a4 = fmaf(w5, bf16lo(v5.z), a4); a5 = fmaf(w5, bf16hi(v5.z), a5);
        a6 = fmaf(w5, bf16lo(v5.w), a6); a7 = fmaf(w5, bf16hi(v5.w), a7);
        a0 = fmaf(w6, bf16lo(v6.x), a0); a1 = fmaf(w6, bf16hi(v6.x), a1);
        a2 = fmaf(w6, bf16lo(v6.y), a2); a3 = fmaf(w6, bf16hi(v6.y), a3);
        a4 = fmaf(w6, bf16lo(v6.z), a4); a5 = fmaf(w6, bf16hi(v6.z), a5);
        a6 = fmaf(w6, bf16lo(v6.w), a6); a7 = fmaf(w6, bf16hi(v6.w), a7);
        a0 = fmaf(w7, bf16lo(v7.x), a0); a1 = fmaf(w7, bf16hi(v7.x), a1);
        a2 = fmaf(w7, bf16lo(v7.y), a2); a3 = fmaf(w7, bf16hi(v7.y), a3);
        a4 = fmaf(w7, bf16lo(v7.z), a4); a5 = fmaf(w7, bf16hi(v7.z), a5);
        a6 = fmaf(w7, bf16lo(v7.w), a6); a7 = fmaf(w7, bf16hi(v7.w), a7);
    }

    float4 bv0 = ((const float4*)bias)[j * 2];
    float4 bv1 = ((const float4*)bias)[j * 2 + 1];
    a0 += bv0.x; a1 += bv0.y; a2 += bv0.z; a3 += bv0.w;
    a4 += bv1.x; a5 += bv1.y; a6 += bv1.z; a7 += bv1.w;
    if (RELU) {
        a0 = fmaxf(a0, 0.f); a1 = fmaxf(a1, 0.f);
        a2 = fmaxf(a2, 0.f); a3 = fmaxf(a3, 0.f);
        a4 = fmaxf(a4, 0.f); a5 = fmaxf(a5, 0.f);
        a6 = fmaxf(a6, 0.f); a7 = fmaxf(a7, 0.f);
    }
    *(float4*)(outX + (size_t)node * FEAT + j * 8)     = make_float4(a0, a1, a2, a3);
    *(float4*)(outX + (size_t)node * FEAT + j * 8 + 4) = make_float4(a4, a5, a6, a7);
}

// ---------------------------------------------------------------- readout v3
__global__ __launch_bounds__(256) void readout_kernel(const float* __restrict__ h,
                                                      const int* __restrict__ batch,
                                                      float* __restrict__ ro, int N) {
    __shared__ float part[128];
    const int g = blockIdx.x;
    const int j = threadIdx.x & 127;
    const int half = threadIdx.x >> 7;
    int lo = 0, hi = N;
    while (lo < hi) { int mid = (lo + hi) >> 1; if (batch[mid] < g) lo = mid + 1; else hi = mid; }
    int lo2 = lo, hi2 = N;
    while (lo2 < hi2) { int mid = (lo2 + hi2) >> 1; if (batch[mid] < g + 1) lo2 = mid + 1; else hi2 = mid; }

    float s0 = 0.f, s1 = 0.f;
    int n = lo + half;
    for (; n + 2 < lo2; n += 4) {
        s0 += h[(size_t)n * FEAT + j];
        s1 += h[(size_t)(n + 2) * FEAT + j];
    }
    if (n < lo2) s0 += h[(size_t)n * FEAT + j];
    float s = s0 + s1;
    if (half == 1) part[j] = s;
    __syncthreads();
    if (half == 0) ro[(size_t)g * FEAT + j] = s + part[j];
}

// ---------------------------------------------------------------- launch
static inline size_t align256(size_t x) { return (x + 255) & ~(size_t)255; }

extern "C" void kernel_launch(void* const* d_in, const int* in_sizes, int n_in,
                              void* d_out, int out_size, void* d_ws, size_t ws_size,
                              hipStream_t stream) {
    const float* gx    = (const float*)d_in[0];
    const int*   ei    = (const int*)d_in[1];
    const int*   batch = (const int*)d_in[2];
    const float* ew    = (const float*)d_in[3];
    const float* W1 = (const float*)d_in[4];
    const float* b1 = (const float*)d_in[5];
    const float* W2 = (const float*)d_in[6];
    const float* b2 = (const float*)d_in[7];
    const float* W3 = (const float*)d_in[8];
    const float* b3 = (const float*)d_in[9];

    const int N = in_sizes[0] / FEAT;            // 50000
    const int E = in_sizes[3];                   // 800000
    const int G = (out_size - N * FEAT) / FEAT;  // 256

    const int* row = ei;
    const int* col = ei + E;

    const int nbuck = (N + 255) >> 8;            // 196
    const int nblk  = (E + EPB - 1) / EPB;       // 782
    const int M     = nbuck * nblk;              // 153,272
    const int snb   = (M + 255) / 256;           // 599 (<= 1024)

    // ---- workspace layout
    char* ws = (char*)d_ws;
    int*   rowptr = (int*)ws;         ws += align256((size_t)(N + 1) * 4);
    float* dinv   = (float*)ws;       ws += align256((size_t)N * 4);
    int*   ghist  = (int*)ws;         ws += align256((size_t)M * 4);
    int*   gsc    = (int*)ws;         ws += align256((size_t)M * 4);
    int*   bsum   = (int*)ws;         ws += align256(1024 * 4);
    uint2* bedge  = (uint2*)ws;       ws += align256((size_t)E * 8);
    uint2* sedge  = (uint2*)ws;       ws += align256((size_t)E * 8);
    unsigned int* hb = (unsigned int*)ws;  ws += align256((size_t)N * 64 * 4);
    float* bufX   = (float*)ws;       ws += align256((size_t)N * FEAT * 4);
    unsigned short* Wh = (unsigned short*)ws; ws += align256((size_t)3 * 16384 * 2);
    unsigned short* Wl = (unsigned short*)ws; ws += align256((size_t)3 * 16384 * 2);

    float* h_out = (float*)d_out;
    float* ro    = h_out + (size_t)N * FEAT;

    // ---- bucket-sorted CSR build v2 (782-block phases, nt scatter stores)
    hist_kernel<<<nblk + 16, 256, 0, stream>>>(col, ghist, W1, W2, W3, Wh, Wl, E, nblk, nbuck);
    scan_block_kernel<<<snb, 256, 0, stream>>>(ghist, gsc, bsum, M);
    scan_bsum_kernel<<<1, 256, 0, stream>>>(bsum, snb);
    scatter1_kernel<<<nblk, 256, 0, stream>>>(row, col, ew, gsc, bsum, bedge, E, nblk, nbuck);
    bucket_kernel<<<nbuck, 1024, 0, stream>>>(bedge, gsc, bsum, rowptr, dinv, sedge, N, E, nblk, nbuck);

    dim3 ggrid((N + 63) / 64, 2);
    const int ablocks = (N + 15) / 16;
    const uint4* hb4 = (const uint4*)hb;

    // ---- layer 1
    gemm_mfma_kernel<<<ggrid, 256, 0, stream>>>(gx, Wh, Wl, dinv, hb, N);
    agg_kernel<1><<<ablocks, 256, 0, stream>>>(rowptr, sedge, hb4, b1, bufX, N);
    // ---- layer 2
    gemm_mfma_kernel<<<ggrid, 256, 0, stream>>>(bufX, Wh + 16384, Wl + 16384, dinv, hb, N);
    agg_kernel<1><<<ablocks, 256, 0, stream>>>(rowptr, sedge, hb4, b2, bufX, N);
    // ---- layer 3
    gemm_mfma_kernel<<<ggrid, 256, 0, stream>>>(bufX, Wh + 32768, Wl + 32768, dinv, hb, N);
    agg_kernel<0><<<ablocks, 256, 0, stream>>>(rowptr, sedge, hb4, b3, h_out, N);
    // ---- readout: one block per graph, atomic-free
    readout_kernel<<<G, 256, 0, stream>>>(h_out, batch, ro, N);
}

// Round 11
// 278.635 us; speedup vs baseline: 1.5476x; 1.1141x over previous
//
#include <hip/hip_runtime.h>

#define FEAT 128
#define EPB 1024   // edges per hist/scatter block (782 blocks -> ~3/CU)

typedef __attribute__((ext_vector_type(8))) short short8;   // 8 bf16 = 4 VGPRs
typedef __attribute__((ext_vector_type(4))) float f32x4;

__device__ __forceinline__ unsigned int bf16rtn(float f) {
    unsigned int u = __float_as_uint(f);
    return (u + 0x7fffu + ((u >> 16) & 1u)) >> 16;   // round-to-nearest-even
}
__device__ __forceinline__ float bf16tof(unsigned int h) { return __uint_as_float(h << 16); }
__device__ __forceinline__ float bf16lo(unsigned int v) { return __uint_as_float(v << 16); }
__device__ __forceinline__ float bf16hi(unsigned int v) { return __uint_as_float(v & 0xffff0000u); }

// ---------------------------------------------------------------- K1: hist + weight prep
// blocks 0..nblk-1: 1024-edge LDS histogram. blocks nblk..nblk+15: weights ->
// transposed bf16 hi/lo planes. (normal stores everywhere — R10's nt regressed)
__global__ __launch_bounds__(256) void hist_kernel(const int* __restrict__ col,
                                                   int* __restrict__ ghist,
                                                   const float* __restrict__ W0,
                                                   const float* __restrict__ W1,
                                                   const float* __restrict__ W2,
                                                   unsigned short* __restrict__ Whi,
                                                   unsigned short* __restrict__ Wlo,
                                                   int E, int nblk, int nbuck) {
    __shared__ int h[256];
    const int t = threadIdx.x, b = blockIdx.x;
    if (b >= nblk) {
        int bb = b - nblk;                            // 0..15
#pragma unroll
        for (int q = 0; q < 12; ++q) {
            int gi = (bb * 12 + q) * 256 + t;         // 0..49151 = 3*16384
            int which = gi >> 14;
            int i = gi & 16383;
            int c = i >> 7, k = i & 127;
            const float* W = (which == 0) ? W0 : (which == 1) ? W1 : W2;
            float w = W[(size_t)k * FEAT + c];
            unsigned int hh = bf16rtn(w);
            size_t off = (size_t)which * 16384 + (size_t)c * FEAT + k;
            Whi[off] = (unsigned short)hh;
            Wlo[off] = (unsigned short)bf16rtn(w - bf16tof(hh));
        }
        return;
    }
    h[t] = 0;
    __syncthreads();
    const int base = b * EPB;
#pragma unroll
    for (int i = 0; i < 4; ++i) {
        int e = base + i * 256 + t;
        if (e < E) atomicAdd(&h[col[e] >> 8], 1);
    }
    __syncthreads();
    if (t < nbuck) ghist[t * nblk + b] = h[t];   // digit-major for the scan
}

// K2: per-256-chunk exclusive scan of ghist -> gsc; raw chunk sums -> bsum.
__global__ __launch_bounds__(256) void scan_block_kernel(const int* __restrict__ cnt,
                                                         int* __restrict__ out,
                                                         int* __restrict__ bsum, int M) {
    __shared__ int s[256];
    int t = threadIdx.x;
    int i = blockIdx.x * 256 + t;
    int own = (i < M) ? cnt[i] : 0;
    s[t] = own;
    for (int off = 1; off < 256; off <<= 1) {
        __syncthreads();
        int v = (t >= off) ? s[t - off] : 0;
        __syncthreads();
        s[t] += v;
    }
    __syncthreads();
    if (i < M) out[i] = s[t] - own;
    if (t == 255) bsum[blockIdx.x] = s[255];
}

// K2b: exclusive scan of bsum in place (nb <= 1024; 4 elements/thread)
__global__ __launch_bounds__(256) void scan_bsum_kernel(int* __restrict__ bsum, int nb) {
    __shared__ int s[256];
    int t = threadIdx.x;
    int i0 = 4 * t;
    int v0 = (i0 + 0 < nb) ? bsum[i0 + 0] : 0;
    int v1 = (i0 + 1 < nb) ? bsum[i0 + 1] : 0;
    int v2 = (i0 + 2 < nb) ? bsum[i0 + 2] : 0;
    int v3 = (i0 + 3 < nb) ? bsum[i0 + 3] : 0;
    int sum = v0 + v1 + v2 + v3;
    s[t] = sum;
    for (int off = 1; off < 256; off <<= 1) {
        __syncthreads();
        int v = (t >= off) ? s[t - off] : 0;
        __syncthreads();
        s[t] += v;
    }
    __syncthreads();
    int excl = s[t] - sum;
    if (i0 + 0 < nb) bsum[i0 + 0] = excl;
    if (i0 + 1 < nb) bsum[i0 + 1] = excl + v0;
    if (i0 + 2 < nb) bsum[i0 + 2] = excl + v0 + v1;
    if (i0 + 3 < nb) bsum[i0 + 3] = excl + v0 + v1 + v2;
}

// K3: scatter into bucket-grouped order (782 blocks; bsum pre-scanned).
__global__ __launch_bounds__(256) void scatter1_kernel(const int* __restrict__ row,
                                                       const int* __restrict__ col,
                                                       const float* __restrict__ ew,
                                                       const int* __restrict__ gsc,
                                                       const int* __restrict__ bsum,
                                                       uint2* __restrict__ bedge,
                                                       int E, int nblk, int nbuck) {
    __shared__ int cur[256];
    const int t = threadIdx.x, b = blockIdx.x;
    if (t < nbuck) {
        int idx = t * nblk + b;
        cur[t] = gsc[idx] + bsum[idx >> 8];
    }
    __syncthreads();
    const int base = b * EPB;
#pragma unroll
    for (int i = 0; i < 4; ++i) {
        int e = base + i * 256 + t;
        if (e < E) {
            int c = col[e];
            int slot = atomicAdd(&cur[c >> 8], 1);
            bedge[slot] = make_uint2(((unsigned)c << 16) | (unsigned)row[e],
                                     __float_as_uint(ew[e]));
        }
    }
}

// K4: per-bucket (256 threads — R6 form) count + weighted degree -> rowptr +
// dinv; then per-node scatter with w*dinv[col] folded in. bsum pre-scanned.
__global__ __launch_bounds__(256) void bucket_kernel(const uint2* __restrict__ bedge,
                                                     const int* __restrict__ gsc,
                                                     const int* __restrict__ bsum,
                                                     int* __restrict__ rowptr,
                                                     float* __restrict__ dinv,
                                                     uint2* __restrict__ sedge,
                                                     int N, int E, int nblk, int nbuck) {
    __shared__ int lcnt[256];
    __shared__ float lw[256];
    __shared__ int lscan[256];
    __shared__ int lcur[256];
    __shared__ float ldv[256];

    const int d = blockIdx.x, t = threadIdx.x;
    const int i0 = d * nblk;
    const int base = gsc[i0] + bsum[i0 >> 8];
    int end;
    if (d == nbuck - 1) end = E;
    else {
        const int i1 = (d + 1) * nblk;
        end = gsc[i1] + bsum[i1 >> 8];
    }

    lcnt[t] = 0;
    lw[t] = 0.f;
    __syncthreads();
    for (int i = base + t; i < end; i += 256) {
        uint2 p = bedge[i];
        int c = (p.x >> 16) & 255;
        atomicAdd(&lcnt[c], 1);
        atomicAdd(&lw[c], __uint_as_float(p.y));
    }
    __syncthreads();
    int own = lcnt[t];
    lscan[t] = own;
    for (int off = 1; off < 256; off <<= 1) {
        __syncthreads();
        int v = (t >= off) ? lscan[t - off] : 0;
        __syncthreads();
        lscan[t] += v;
    }
    __syncthreads();
    int excl = lscan[t] - own;
    lcur[t] = base + excl;
    float wsum = lw[t];
    float dv = (wsum > 0.f) ? rsqrtf(wsum) : 0.f;
    ldv[t] = dv;
    int node = d * 256 + t;
    if (node < N) {
        rowptr[node] = base + excl;
        dinv[node] = dv;
    }
    if (d == nbuck - 1 && t == 0) rowptr[N] = E;
    __syncthreads();
    for (int i = base + t; i < end; i += 256) {
        uint2 p = bedge[i];
        int c = (p.x >> 16) & 255;
        int slot = atomicAdd(&lcur[c], 1);
        sedge[slot] = make_uint2(p.x & 0xFFFFu,
                                 __float_as_uint(__uint_as_float(p.y) * ldv[c]));
    }
}

// ---------------------------------------------------------------- MFMA GEMM v3 (verified, ~12.5us)
// grid (782,2) = 1564 blocks. A-fragments from global fp32, split hi/lo
// in-register; 32KB W LDS; epilogue folds dinv[row].
__global__ __launch_bounds__(256) void gemm_mfma_kernel(
    const float* __restrict__ X,
    const unsigned short* __restrict__ Wthi, const unsigned short* __restrict__ Wtlo,
    const float* __restrict__ dinv,
    unsigned int* __restrict__ hb,   // N x 64 packed bf16 out
    int N)
{
    __shared__ unsigned short wh[64 * 128];
    __shared__ unsigned short wl[64 * 128];

    const int tid = threadIdx.x;
    const int r0 = blockIdx.x * 64;
    const int cb = blockIdx.y;       // col half: 0 or 1

#pragma unroll
    for (int it = 0; it < 4; ++it) {
        int idx = it * 256 + tid;
        int c = idx >> 4;
        int k8 = (idx & 15) * 8;
        int sw = k8 ^ ((c & 7) << 3);
        size_t src = (size_t)(cb * 64 + c) * FEAT + k8;
        *(short8*)&wh[c * 128 + sw] = *(const short8*)(Wthi + src);
        *(short8*)&wl[c * 128 + sw] = *(const short8*)(Wtlo + src);
    }
    __syncthreads();

    const int lane = tid & 63;
    const int wv = tid >> 6;
    const int m = lane & 15;
    const int quad = lane >> 4;
    const int arow = wv * 16 + m;
    const int grow = r0 + arow;
    const float* xrow = X + (size_t)grow * FEAT;

    f32x4 acc[4];
#pragma unroll
    for (int ct = 0; ct < 4; ++ct) acc[ct] = (f32x4){0.f, 0.f, 0.f, 0.f};

#pragma unroll
    for (int kt = 0; kt < 4; ++kt) {
        const int k0 = kt * 32 + quad * 8;
        float4 va = make_float4(0.f, 0.f, 0.f, 0.f);
        float4 vb = make_float4(0.f, 0.f, 0.f, 0.f);
        if (grow < N) {
            va = *(const float4*)(xrow + k0);
            vb = *(const float4*)(xrow + k0 + 4);
        }
        unsigned int h0 = bf16rtn(va.x), h1 = bf16rtn(va.y);
        unsigned int h2 = bf16rtn(va.z), h3 = bf16rtn(va.w);
        unsigned int h4 = bf16rtn(vb.x), h5 = bf16rtn(vb.y);
        unsigned int h6 = bf16rtn(vb.z), h7 = bf16rtn(vb.w);
        short8 ah, al;
        ah[0] = (short)h0; ah[1] = (short)h1; ah[2] = (short)h2; ah[3] = (short)h3;
        ah[4] = (short)h4; ah[5] = (short)h5; ah[6] = (short)h6; ah[7] = (short)h7;
        al[0] = (short)bf16rtn(va.x - bf16tof(h0));
        al[1] = (short)bf16rtn(va.y - bf16tof(h1));
        al[2] = (short)bf16rtn(va.z - bf16tof(h2));
        al[3] = (short)bf16rtn(va.w - bf16tof(h3));
        al[4] = (short)bf16rtn(vb.x - bf16tof(h4));
        al[5] = (short)bf16rtn(vb.y - bf16tof(h5));
        al[6] = (short)bf16rtn(vb.z - bf16tof(h6));
        al[7] = (short)bf16rtn(vb.w - bf16tof(h7));
#pragma unroll
        for (int ct = 0; ct < 4; ++ct) {
            int bc = ct * 16 + m;
            int bw = k0 ^ ((bc & 7) << 3);
            short8 bh = *(const short8*)&wh[bc * 128 + bw];
            short8 bl = *(const short8*)&wl[bc * 128 + bw];
            acc[ct] = __builtin_amdgcn_mfma_f32_16x16x32_bf16(ah, bh, acc[ct], 0, 0, 0);
            acc[ct] = __builtin_amdgcn_mfma_f32_16x16x32_bf16(ah, bl, acc[ct], 0, 0, 0);
            acc[ct] = __builtin_amdgcn_mfma_f32_16x16x32_bf16(al, bh, acc[ct], 0, 0, 0);
        }
    }

    const int rbase = wv * 16 + quad * 4;
    const int grb = r0 + rbase;
    float dv0, dv1, dv2, dv3;
    if (grb + 3 < N) {
        float4 d4 = *(const float4*)(dinv + grb);
        dv0 = d4.x; dv1 = d4.y; dv2 = d4.z; dv3 = d4.w;
    } else {
        dv0 = (grb + 0 < N) ? dinv[grb + 0] : 0.f;
        dv1 = (grb + 1 < N) ? dinv[grb + 1] : 0.f;
        dv2 = (grb + 2 < N) ? dinv[grb + 2] : 0.f;
        dv3 = (grb + 3 < N) ? dinv[grb + 3] : 0.f;
    }

    __syncthreads();                 // all waves done reading wh -> reuse as epilogue buf
    unsigned short* cl = wh;         // 64*72*2B = 9.2KB, fits
#pragma unroll
    for (int ct = 0; ct < 4; ++ct) {
        cl[(rbase + 0) * 72 + ct * 16 + m] = (unsigned short)bf16rtn(acc[ct][0] * dv0);
        cl[(rbase + 1) * 72 + ct * 16 + m] = (unsigned short)bf16rtn(acc[ct][1] * dv1);
        cl[(rbase + 2) * 72 + ct * 16 + m] = (unsigned short)bf16rtn(acc[ct][2] * dv2);
        cl[(rbase + 3) * 72 + ct * 16 + m] = (unsigned short)bf16rtn(acc[ct][3] * dv3);
    }
    __syncthreads();
#pragma unroll
    for (int it = 0; it < 2; ++it) {
        int idx = it * 256 + tid;
        int r = idx >> 3;
        int c4 = (idx & 7) * 4;
        int gr = r0 + r;
        if (gr < N) {
            uint4 pv = *(const uint4*)&cl[r * 72 + c4 * 2];
            *(uint4*)(hb + (size_t)gr * 64 + cb * 32 + c4) = pv;
        }
    }
}

// ---------------------------------------------------------------- CSR aggregation v8 (verified, ~38us)
template <int RELU>
__global__ __launch_bounds__(256) void agg_kernel(
    const int* __restrict__ rowptr, const uint2* __restrict__ sedge,
    const uint4* __restrict__ hb4,   // N x 16 uint4 rows (256B packed bf16)
    const float* __restrict__ bias,
    float* __restrict__ outX, int N)
{
    const int node = blockIdx.x * 16 + (threadIdx.x >> 4);
    if (node >= N) return;
    const int j = threadIdx.x & 15;
    const int s = rowptr[node];
    const int e = rowptr[node + 1];

    float a0 = 0.f, a1 = 0.f, a2 = 0.f, a3 = 0.f;
    float a4 = 0.f, a5 = 0.f, a6 = 0.f, a7 = 0.f;

    for (int gb = s; gb < e; gb += 8) {
        uint2 m0, m1, m2, m3, m4, m5, m6, m7;
        if (gb + 8 <= e) {
            m0 = sedge[gb + 0]; m1 = sedge[gb + 1];
            m2 = sedge[gb + 2]; m3 = sedge[gb + 3];
            m4 = sedge[gb + 4]; m5 = sedge[gb + 5];
            m6 = sedge[gb + 6]; m7 = sedge[gb + 7];
        } else {
            const uint2 z = make_uint2(0u, 0u);
            m0 = (gb + 0 < e) ? sedge[gb + 0] : z;
            m1 = (gb + 1 < e) ? sedge[gb + 1] : z;
            m2 = (gb + 2 < e) ? sedge[gb + 2] : z;
            m3 = (gb + 3 < e) ? sedge[gb + 3] : z;
            m4 = (gb + 4 < e) ? sedge[gb + 4] : z;
            m5 = (gb + 5 < e) ? sedge[gb + 5] : z;
            m6 = (gb + 6 < e) ? sedge[gb + 6] : z;
            m7 = (gb + 7 < e) ? sedge[gb + 7] : z;
        }
        uint4 v0 = hb4[(size_t)m0.x * 16 + j];
        uint4 v1 = hb4[(size_t)m1.x * 16 + j];
        uint4 v2 = hb4[(size_t)m2.x * 16 + j];
        uint4 v3 = hb4[(size_t)m3.x * 16 + j];
        uint4 v4 = hb4[(size_t)m4.x * 16 + j];
        uint4 v5 = hb4[(size_t)m5.x * 16 + j];
        uint4 v6 = hb4[(size_t)m6.x * 16 + j];
        uint4 v7 = hb4[(size_t)m7.x * 16 + j];
        float w0 = __uint_as_float(m0.y), w1 = __uint_as_float(m1.y);
        float w2 = __uint_as_float(m2.y), w3 = __uint_as_float(m3.y);
        float w4 = __uint_as_float(m4.y), w5 = __uint_as_float(m5.y);
        float w6 = __uint_as_float(m6.y), w7 = __uint_as_float(m7.y);
        a0 = fmaf(w0, bf16lo(v0.x), a0); a1 = fmaf(w0, bf16hi(v0.x), a1);
        a2 = fmaf(w0, bf16lo(v0.y), a2); a3 = fmaf(w0, bf16hi(v0.y), a3);
        a4 = fmaf(w0, bf16lo(v0.z), a4); a5 = fmaf(w0, bf16hi(v0.z), a5);
        a6 = fmaf(w0, bf16lo(v0.w), a6); a7 = fmaf(w0, bf16hi(v0.w), a7);
        a0 = fmaf(w1, bf16lo(v1.x), a0); a1 = fmaf(w1, bf16hi(v1.x), a1);
        a2 = fmaf(w1, bf16lo(v1.y), a2); a3 = fmaf(w1, bf16hi(v1.y), a3);
        a4 = fmaf(w1, bf16lo(v1.z), a4); a5 = fmaf(w1, bf16hi(v1.z), a5);
        a6 = fmaf(w1, bf16lo(v1.w), a6); a7 = fmaf(w1, bf16hi(v1.w), a7);
        a0 = fmaf(w2, bf16lo(v2.x), a0); a1 = fmaf(w2, bf16hi(v2.x), a1);
        a2 = fmaf(w2, bf16lo(v2.y), a2); a3 = fmaf(w2, bf16hi(v2.y), a3);
        a4 = fmaf(w2, bf16lo(v2.z), a4); a5 = fmaf(w2, bf16hi(v2.z), a5);
        a6 = fmaf(w2, bf16lo(v2.w), a6); a7 = fmaf(w2, bf16hi(v2.w), a7);
        a0 = fmaf(w3, bf16lo(v3.x), a0); a1 = fmaf(w3, bf16hi(v3.x), a1);
        a2 = fmaf(w3, bf16lo(v3.y), a2); a3 = fmaf(w3, bf16hi(v3.y), a3);
        a4 = fmaf(w3, bf16lo(v3.z), a4); a5 = fmaf(w3, bf16hi(v3.z), a5);
        a6 = fmaf(w3, bf16lo(v3.w), a6); a7 = fmaf(w3, bf16hi(v3.w), a7);
        a0 = fmaf(w4, bf16lo(v4.x), a0); a1 = fmaf(w4, bf16hi(v4.x), a1);
        a2 = fmaf(w4, bf16lo(v4.y), a2); a3 = fmaf(w4, bf16hi(v4.y), a3);
        a4 = fmaf(w4, bf16lo(v4.z), a4); a5 = fmaf(w4, bf16hi(v4.z), a5);
        a6 = fmaf(w4, bf16lo(v4.w), a6); a7 = fmaf(w4, bf16hi(v4.w), a7);
        a0 = fmaf(w5, bf16lo(v5.x), a0); a1 = fmaf(w5, bf16hi(v5.x), a1);
        a2 = fmaf(w5, bf16lo(v5.y), a2); a3 = fmaf(w5, bf16hi(v5.y), a3);
        a4 = fmaf(w5, bf16lo(v5.z), a4); a5 = fmaf(w5, bf16hi(v5.z), a5);
        a6 = fmaf(w5, bf16lo(v5.w), a6); a7 = fmaf(w5, bf16hi(v5.w), a7);
        a0 = fmaf(w6, bf16lo(v6.x), a0); a1 = fmaf(w6, bf16hi(v6.x), a1);
        a2 = fmaf(w6, bf16lo(v6.y), a2); a3 = fmaf(w6, bf16hi(v6.y), a3);
        a4 = fmaf(w6, bf16lo(v6.z), a4); a5 = fmaf(w6, bf16hi(v6.z), a5);
        a6 = fmaf(w6, bf16lo(v6.w), a6); a7 = fmaf(w6, bf16hi(v6.w), a7);
        a0 = fmaf(w7, bf16lo(v7.x), a0); a1 = fmaf(w7, bf16hi(v7.x), a1);
        a2 = fmaf(w7, bf16lo(v7.y), a2); a3 = fmaf(w7, bf16hi(v7.y), a3);
        a4 = fmaf(w7, bf16lo(v7.z), a4); a5 = fmaf(w7, bf16hi(v7.z), a5);
        a6 = fmaf(w7, bf16lo(v7.w), a6); a7 = fmaf(w7, bf16hi(v7.w), a7);
    }

    float4 bv0 = ((const float4*)bias)[j * 2];
    float4 bv1 = ((const float4*)bias)[j * 2 + 1];
    a0 += bv0.x; a1 += bv0.y; a2 += bv0.z; a3 += bv0.w;
    a4 += bv1.x; a5 += bv1.y; a6 += bv1.z; a7 += bv1.w;
    if (RELU) {
        a0 = fmaxf(a0, 0.f); a1 = fmaxf(a1, 0.f);
        a2 = fmaxf(a2, 0.f); a3 = fmaxf(a3, 0.f);
        a4 = fmaxf(a4, 0.f); a5 = fmaxf(a5, 0.f);
        a6 = fmaxf(a6, 0.f); a7 = fmaxf(a7, 0.f);
    }
    *(float4*)(outX + (size_t)node * FEAT + j * 8)     = make_float4(a0, a1, a2, a3);
    *(float4*)(outX + (size_t)node * FEAT + j * 8 + 4) = make_float4(a4, a5, a6, a7);
}

// ---------------------------------------------------------------- readout v3
__global__ __launch_bounds__(256) void readout_kernel(const float* __restrict__ h,
                                                      const int* __restrict__ batch,
                                                      float* __restrict__ ro, int N) {
    __shared__ float part[128];
    const int g = blockIdx.x;
    const int j = threadIdx.x & 127;
    const int half = threadIdx.x >> 7;
    int lo = 0, hi = N;
    while (lo < hi) { int mid = (lo + hi) >> 1; if (batch[mid] < g) lo = mid + 1; else hi = mid; }
    int lo2 = lo, hi2 = N;
    while (lo2 < hi2) { int mid = (lo2 + hi2) >> 1; if (batch[mid] < g + 1) lo2 = mid + 1; else hi2 = mid; }

    float s0 = 0.f, s1 = 0.f;
    int n = lo + half;
    for (; n + 2 < lo2; n += 4) {
        s0 += h[(size_t)n * FEAT + j];
        s1 += h[(size_t)(n + 2) * FEAT + j];
    }
    if (n < lo2) s0 += h[(size_t)n * FEAT + j];
    float s = s0 + s1;
    if (half == 1) part[j] = s;
    __syncthreads();
    if (half == 0) ro[(size_t)g * FEAT + j] = s + part[j];
}

// ---------------------------------------------------------------- launch
static inline size_t align256(size_t x) { return (x + 255) & ~(size_t)255; }

extern "C" void kernel_launch(void* const* d_in, const int* in_sizes, int n_in,
                              void* d_out, int out_size, void* d_ws, size_t ws_size,
                              hipStream_t stream) {
    const float* gx    = (const float*)d_in[0];
    const int*   ei    = (const int*)d_in[1];
    const int*   batch = (const int*)d_in[2];
    const float* ew    = (const float*)d_in[3];
    const float* W1 = (const float*)d_in[4];
    const float* b1 = (const float*)d_in[5];
    const float* W2 = (const float*)d_in[6];
    const float* b2 = (const float*)d_in[7];
    const float* W3 = (const float*)d_in[8];
    const float* b3 = (const float*)d_in[9];

    const int N = in_sizes[0] / FEAT;            // 50000
    const int E = in_sizes[3];                   // 800000
    const int G = (out_size - N * FEAT) / FEAT;  // 256

    const int* row = ei;
    const int* col = ei + E;

    const int nbuck = (N + 255) >> 8;            // 196
    const int nblk  = (E + EPB - 1) / EPB;       // 782
    const int M     = nbuck * nblk;              // 153,272
    const int snb   = (M + 255) / 256;           // 599 (<= 1024)

    // ---- workspace layout
    char* ws = (char*)d_ws;
    int*   rowptr = (int*)ws;         ws += align256((size_t)(N + 1) * 4);
    float* dinv   = (float*)ws;       ws += align256((size_t)N * 4);
    int*   ghist  = (int*)ws;         ws += align256((size_t)M * 4);
    int*   gsc    = (int*)ws;         ws += align256((size_t)M * 4);
    int*   bsum   = (int*)ws;         ws += align256(1024 * 4);
    uint2* bedge  = (uint2*)ws;       ws += align256((size_t)E * 8);
    uint2* sedge  = (uint2*)ws;       ws += align256((size_t)E * 8);
    unsigned int* hb = (unsigned int*)ws;  ws += align256((size_t)N * 64 * 4);
    float* bufX   = (float*)ws;       ws += align256((size_t)N * FEAT * 4);
    unsigned short* Wh = (unsigned short*)ws; ws += align256((size_t)3 * 16384 * 2);
    unsigned short* Wl = (unsigned short*)ws; ws += align256((size_t)3 * 16384 * 2);

    float* h_out = (float*)d_out;
    float* ro    = h_out + (size_t)N * FEAT;

    // ---- bucket-sorted CSR build (782-block hist/scatter; normal stores)
    hist_kernel<<<nblk + 16, 256, 0, stream>>>(col, ghist, W1, W2, W3, Wh, Wl, E, nblk, nbuck);
    scan_block_kernel<<<snb, 256, 0, stream>>>(ghist, gsc, bsum, M);
    scan_bsum_kernel<<<1, 256, 0, stream>>>(bsum, snb);
    scatter1_kernel<<<nblk, 256, 0, stream>>>(row, col, ew, gsc, bsum, bedge, E, nblk, nbuck);
    bucket_kernel<<<nbuck, 256, 0, stream>>>(bedge, gsc, bsum, rowptr, dinv, sedge, N, E, nblk, nbuck);

    dim3 ggrid((N + 63) / 64, 2);
    const int ablocks = (N + 15) / 16;
    const uint4* hb4 = (const uint4*)hb;

    // ---- layer 1
    gemm_mfma_kernel<<<ggrid, 256, 0, stream>>>(gx, Wh, Wl, dinv, hb, N);
    agg_kernel<1><<<ablocks, 256, 0, stream>>>(rowptr, sedge, hb4, b1, bufX, N);
    // ---- layer 2
    gemm_mfma_kernel<<<ggrid, 256, 0, stream>>>(bufX, Wh + 16384, Wl + 16384, dinv, hb, N);
    agg_kernel<1><<<ablocks, 256, 0, stream>>>(rowptr, sedge, hb4, b2, bufX, N);
    // ---- layer 3
    gemm_mfma_kernel<<<ggrid, 256, 0, stream>>>(bufX, Wh + 32768, Wl + 32768, dinv, hb, N);
    agg_kernel<0><<<ablocks, 256, 0, stream>>>(rowptr, sedge, hb4, b3, h_out, N);
    // ---- readout: one block per graph, atomic-free
    readout_kernel<<<G, 256, 0, stream>>>(h_out, batch, ro, N);
}